// Round 5
// baseline (1552.511 us; speedup 1.0000x reference)
//
#include <hip/hip_runtime.h>
#include <hip/hip_bf16.h>

#define DEV __device__ __forceinline__

DEV float bf2f(__hip_bfloat16 v) { return __bfloat162float(v); }
DEV float lrelu(float x) { return x > 0.f ? x : 0.2f * x; }
DEV float eluf(float x) { return x > 0.f ? x : (__expf(x) - 1.f); }

// Read element i of a float tensor that is either bf16 (f=1) or fp32 (f=0).
DEV float ldf(const void* p, int i, int f) {
    return f ? bf2f(((const __hip_bfloat16*)p)[i]) : ((const float*)p)[i];
}

// Inline dtype detection (see r2 notes): bf16 low-half exponent test, 64 samples.
DEV int detect_bf16(const void* p) {
    const unsigned int* w = (const unsigned int*)p;
    unsigned int e = (w[threadIdx.x & 63] >> 7) & 0xFFu;
    int hit = (e >= 112u && e <= 130u) ? 1 : 0;
    unsigned long long b = __ballot(hit);
    return __popcll(b) > 32 ? 1 : 0;
}

// ---------------- param conversion ----------------

struct Ptrs15 { const void* p[15]; };  // [14] = x1 (for detection)

#define P_W0 0
#define P_W1 4096
#define P_W2 12288
#define P_AS0 14336
#define P_AD0 14400
#define P_B0 14464
#define P_AS1 14528
#define P_AD1 14592
#define P_B1 14656
#define P_AS2 14720
#define P_AD2 14736
#define P_B2 14752
#define P_GAMMA 14768
#define P_BETA 14784
#define P_TOTAL 14800

__global__ void k_params(Ptrs15 pp, float* __restrict__ P) {
    const int narr[14] = {4096, 8192, 2048, 64, 64, 64, 64, 64, 64, 16, 16, 16, 16, 16};
    const int oarr[14] = {P_W0, P_W1, P_W2, P_AS0, P_AD0, P_B0, P_AS1, P_AD1, P_B1,
                          P_AS2, P_AD2, P_B2, P_GAMMA, P_BETA};
    int f = detect_bf16(pp.p[14]);
    int b = blockIdx.x;
    const void* src = pp.p[b];
    int nn = narr[b], oo = oarr[b];
    for (int i = threadIdx.x; i < nn; i += blockDim.x)
        P[oo + i] = ldf(src, i, f);
}

// ---------------- CSR build: bucket scatter (streaming writes, no line waste) ----------------
// Bucket = dst >> 8 (256 nodes/bucket). CAP=6144 vs mean load 4092 (+32 sigma, uniform dst).

#define CAP 6144

__global__ __launch_bounds__(256) void k_scatter(
    const int* __restrict__ ei1, const int* __restrict__ ei2, int E,
    int* __restrict__ bfill1, int* __restrict__ bfill2,
    int2* __restrict__ bedge1, int2* __restrict__ bedge2)
{
    int stride = gridDim.x * blockDim.x;
    for (int i = blockIdx.x * blockDim.x + threadIdx.x; i < 2 * E; i += stride) {
        const int* ei; int j; int* bfill; int2* bedge;
        if (i < E) { ei = ei1; j = i; bfill = bfill1; bedge = bedge1; }
        else       { ei = ei2; j = i - E; bfill = bfill2; bedge = bedge2; }
        int s = ei[j], d = ei[E + j];
        int b = d >> 8;
        int pos = atomicAdd(&bfill[b], 1);
        if (pos < CAP) bedge[(size_t)b * CAP + pos] = make_int2(s, d);
    }
}

// One block per bucket: LDS degree count + scan + scatter into a contiguous,
// L2-resident 24KB window of the padded col array. Writes rowptr/deg too.
__global__ __launch_bounds__(256) void k_bucket2(
    const int* __restrict__ bfill1, const int2* __restrict__ bedge1,
    int* __restrict__ rp1, int* __restrict__ dg1, int* __restrict__ col1,
    const int* __restrict__ bfill2, const int2* __restrict__ bedge2,
    int* __restrict__ rp2, int* __restrict__ dg2, int* __restrict__ col2,
    int nb, int N)
{
    int b = blockIdx.x;
    const int* bfill; const int2* bedge; int* rowptr; int* deg; int* col;
    if (b < nb) { bfill = bfill1; bedge = bedge1; rowptr = rp1; deg = dg1; col = col1; }
    else { b -= nb; bfill = bfill2; bedge = bedge2; rowptr = rp2; deg = dg2; col = col2; }

    __shared__ int ldeg[256], lscan[256], lfill[256];
    int t = threadIdx.x;
    ldeg[t] = 0;
    __syncthreads();

    int cnt = min(bfill[b], CAP);
    const int2* be = bedge + (size_t)b * CAP;
    for (int e = t; e < cnt; e += 256) atomicAdd(&ldeg[be[e].y & 255], 1);
    __syncthreads();

    int myDeg = ldeg[t];
    lscan[t] = myDeg;
    __syncthreads();
    #pragma unroll
    for (int off = 1; off < 256; off <<= 1) {
        int v = (t >= off) ? lscan[t - off] : 0;
        __syncthreads();
        lscan[t] += v;
        __syncthreads();
    }
    int excl = lscan[t] - myDeg;
    int node = (b << 8) + t;
    int base = b * CAP;
    if (node < N) { rowptr[node] = base + excl; deg[node] = myDeg; }
    lfill[t] = excl;
    __syncthreads();

    for (int e = t; e < cnt; e += 256) {
        int2 ed = be[e];
        int pos = atomicAdd(&lfill[ed.y & 255], 1);
        col[base + pos] = ed.x;
    }
}

// ---------------- persistent templated GEMM (unchanged from r3) ----------------

template <int K, int C, int TR>
__global__ __launch_bounds__(256) void k_gemm(
    const void* __restrict__ A1, const void* __restrict__ A2, int rawMask,
    const float* __restrict__ W, const float* __restrict__ av, const float* __restrict__ dv,
    float* __restrict__ Hout, float* __restrict__ as_, float* __restrict__ ad_,
    int N, int numTiles)
{
    constexpr int CQ = C / 4;
    constexpr int RG = 256 / CQ;
    constexpr int RPT = TR / RG;
    constexpr int PADR = TR + 1;
    __shared__ float Ws[K * C];
    __shared__ float xs[K * PADR];

    int f = 0;
    if (rawMask) f = detect_bf16((rawMask & 1) ? A1 : A2);

    int t = threadIdx.x;
    for (int idx = t; idx < K * C; idx += 256) Ws[idx] = W[idx];

    const int cq = t % CQ, rg = t / CQ;

    for (int tile = blockIdx.x; tile < numTiles; tile += gridDim.x) {
        int rowBase = tile * TR;
        for (int idx = t; idx < K * TR; idx += 256) {
            int rr = idx / K, k = idx % K;
            int row = rowBase + rr;
            float v = 0.f;
            if (row < N) {
                if (k < 64) v = (rawMask & 1) ? ldf(A1, row * 64 + k, f)
                                              : ((const float*)A1)[row * 64 + k];
                else        v = (rawMask & 2) ? ldf(A2, row * 64 + (k - 64), f)
                                              : ((const float*)A2)[row * 64 + (k - 64)];
            }
            xs[k * PADR + rr] = v;
        }
        __syncthreads();

        float acc[RPT][4];
        #pragma unroll
        for (int r = 0; r < RPT; r++)
            for (int c = 0; c < 4; c++) acc[r][c] = 0.f;

        #pragma unroll 4
        for (int k = 0; k < K; k++) {
            float4 wv = *(const float4*)&Ws[k * C + cq * 4];
            #pragma unroll
            for (int r = 0; r < RPT; r++) {
                float xv = xs[k * PADR + rg * RPT + r];
                acc[r][0] += xv * wv.x;
                acc[r][1] += xv * wv.y;
                acc[r][2] += xv * wv.z;
                acc[r][3] += xv * wv.w;
            }
        }

        #pragma unroll
        for (int r = 0; r < RPT; r++) {
            int row = rowBase + rg * RPT + r;
            float4 o = {acc[r][0], acc[r][1], acc[r][2], acc[r][3]};
            float a0 = av[cq * 4], a1 = av[cq * 4 + 1], a2 = av[cq * 4 + 2], a3 = av[cq * 4 + 3];
            float d0 = dv[cq * 4], d1 = dv[cq * 4 + 1], d2 = dv[cq * 4 + 2], d3 = dv[cq * 4 + 3];
            float vs = o.x * a0 + o.y * a1 + o.z * a2 + o.w * a3;
            float vd = o.x * d0 + o.y * d1 + o.z * d2 + o.w * d3;
            #pragma unroll
            for (int off = CQ >> 1; off; off >>= 1) {
                vs += __shfl_xor(vs, off);
                vd += __shfl_xor(vd, off);
            }
            if (row < N) {
                *(float4*)&Hout[(size_t)row * C + cq * 4] = o;
                if (cq == 0) { as_[row] = vs; ad_[row] = vd; }
            }
        }
        __syncthreads();
    }
}

// ---------------- Aggregation F=64 (unchanged from r3) ----------------

__global__ __launch_bounds__(256) void k_agg64(
    const int* __restrict__ rowptr, const int* __restrict__ deg,
    const int* __restrict__ col, const float* __restrict__ as_,
    const float* __restrict__ ad_, const float* __restrict__ h,
    const float* __restrict__ bias, float* __restrict__ out,
    int N, int doElu)
{
    int wid = (blockIdx.x * blockDim.x + threadIdx.x) >> 6;
    int lane = threadIdx.x & 63;
    if (wid >= N) return;
    int start = rowptr[wid];
    int d = deg[wid];
    float adi = ad_[wid];
    float eself = __expf(lrelu(as_[wid] + adi));

    int dc = min(d, 64);
    float w = 0.f; int s = 0;
    if (lane < dc) { s = col[start + lane]; w = __expf(lrelu(as_[s] + adi)); }
    float ssum = w;
    for (int j = lane + 64; j < d; j += 64)
        ssum += __expf(lrelu(as_[col[start + j]] + adi));
    #pragma unroll
    for (int off = 32; off; off >>= 1) ssum += __shfl_xor(ssum, off);
    float inv = 1.f / (ssum + eself + 1e-16f);
    w *= inv;

    int fq = lane & 15, eg = lane >> 4;
    const float4* h4 = (const float4*)h;
    float4 acc = {0.f, 0.f, 0.f, 0.f};
    if (eg == 0) {
        float4 hv = h4[(size_t)wid * 16 + fq];
        float en = eself * inv;
        acc.x = en * hv.x; acc.y = en * hv.y; acc.z = en * hv.z; acc.w = en * hv.w;
    }
    {
        int iters = (dc + 3) >> 2;
        for (int it = 0; it < iters; it++) {
            int j = it * 4 + eg;
            float wj = __shfl(w, j);
            int sj = __shfl(s, j);
            if (j < dc) {
                float4 hv = h4[(size_t)sj * 16 + fq];
                acc.x += wj * hv.x; acc.y += wj * hv.y;
                acc.z += wj * hv.z; acc.w += wj * hv.w;
            }
        }
    }
    for (int base = 64; base < d; base += 64) {
        int cnt = min(64, d - base);
        float w2 = 0.f; int s2 = 0;
        if (lane < cnt) { s2 = col[start + base + lane]; w2 = __expf(lrelu(as_[s2] + adi)) * inv; }
        int iters = (cnt + 3) >> 2;
        for (int it = 0; it < iters; it++) {
            int j = it * 4 + eg;
            float wj = __shfl(w2, j);
            int sj = __shfl(s2, j);
            if (j < cnt) {
                float4 hv = h4[(size_t)sj * 16 + fq];
                acc.x += wj * hv.x; acc.y += wj * hv.y;
                acc.z += wj * hv.z; acc.w += wj * hv.w;
            }
        }
    }
    #pragma unroll
    for (int off = 16; off < 64; off <<= 1) {
        acc.x += __shfl_xor(acc.x, off);
        acc.y += __shfl_xor(acc.y, off);
        acc.z += __shfl_xor(acc.z, off);
        acc.w += __shfl_xor(acc.w, off);
    }
    if (lane < 16) {
        float4 b4 = ((const float4*)bias)[lane];
        float4 o = {acc.x + b4.x, acc.y + b4.y, acc.z + b4.z, acc.w + b4.w};
        if (doElu) { o.x = eluf(o.x); o.y = eluf(o.y); o.z = eluf(o.z); o.w = eluf(o.w); }
        ((float4*)out)[(size_t)wid * 16 + lane] = o;
    }
}

// ---------------- Aggregation F=16 (unchanged from r3) ----------------

__global__ __launch_bounds__(256) void k_agg16(
    const int* __restrict__ rowptr, const int* __restrict__ deg,
    const int* __restrict__ col, const float* __restrict__ as_,
    const float* __restrict__ ad_, const float* __restrict__ h,
    const float* __restrict__ bias, float* __restrict__ out, int N)
{
    int wid = (blockIdx.x * blockDim.x + threadIdx.x) >> 6;
    int lane = threadIdx.x & 63;
    if (wid >= N) return;
    int start = rowptr[wid];
    int d = deg[wid];
    float adi = ad_[wid];
    float eself = __expf(lrelu(as_[wid] + adi));

    int dc = min(d, 64);
    float w = 0.f; int s = 0;
    if (lane < dc) { s = col[start + lane]; w = __expf(lrelu(as_[s] + adi)); }
    float ssum = w;
    for (int j = lane + 64; j < d; j += 64)
        ssum += __expf(lrelu(as_[col[start + j]] + adi));
    #pragma unroll
    for (int off = 32; off; off >>= 1) ssum += __shfl_xor(ssum, off);
    float inv = 1.f / (ssum + eself + 1e-16f);
    w *= inv;

    int fq = lane & 3, eg = lane >> 2;
    const float4* h4 = (const float4*)h;
    float4 acc = {0.f, 0.f, 0.f, 0.f};
    if (eg == 0) {
        float4 hv = h4[(size_t)wid * 4 + fq];
        float en = eself * inv;
        acc.x = en * hv.x; acc.y = en * hv.y; acc.z = en * hv.z; acc.w = en * hv.w;
    }
    {
        int iters = (dc + 15) >> 4;
        for (int it = 0; it < iters; it++) {
            int j = it * 16 + eg;
            float wj = __shfl(w, j);
            int sj = __shfl(s, j);
            if (j < dc) {
                float4 hv = h4[(size_t)sj * 4 + fq];
                acc.x += wj * hv.x; acc.y += wj * hv.y;
                acc.z += wj * hv.z; acc.w += wj * hv.w;
            }
        }
    }
    for (int base = 64; base < d; base += 64) {
        int cnt = min(64, d - base);
        float w2 = 0.f; int s2 = 0;
        if (lane < cnt) { s2 = col[start + base + lane]; w2 = __expf(lrelu(as_[s2] + adi)) * inv; }
        int iters = (cnt + 15) >> 4;
        for (int it = 0; it < iters; it++) {
            int j = it * 16 + eg;
            float wj = __shfl(w2, j);
            int sj = __shfl(s2, j);
            if (j < cnt) {
                float4 hv = h4[(size_t)sj * 4 + fq];
                acc.x += wj * hv.x; acc.y += wj * hv.y;
                acc.z += wj * hv.z; acc.w += wj * hv.w;
            }
        }
    }
    #pragma unroll
    for (int off = 4; off < 64; off <<= 1) {
        acc.x += __shfl_xor(acc.x, off);
        acc.y += __shfl_xor(acc.y, off);
        acc.z += __shfl_xor(acc.z, off);
        acc.w += __shfl_xor(acc.w, off);
    }
    if (lane < 4) {
        float4 b4 = ((const float4*)bias)[lane];
        float4 o = {acc.x + b4.x, acc.y + b4.y, acc.z + b4.z, acc.w + b4.w};
        ((float4*)out)[(size_t)wid * 4 + lane] = o;
    }
}

// ---------------- BatchNorm stats ----------------

__global__ __launch_bounds__(256) void k_bnstat(const float* __restrict__ logits,
                                                float* __restrict__ bn, int N) {
    int t = threadIdx.x;
    int c = t & 15;
    int g = (blockIdx.x * blockDim.x + t) >> 4;
    int stride = (gridDim.x * blockDim.x) >> 4;
    float s = 0.f, s2 = 0.f;
    for (int r = g; r < N; r += stride) {
        float v = logits[r * 16 + c];
        s += v;
        s2 += v * v;
    }
    s += __shfl_xor(s, 16);  s += __shfl_xor(s, 32);
    s2 += __shfl_xor(s2, 16); s2 += __shfl_xor(s2, 32);
    if ((t & 63) < 16) {
        atomicAdd(&bn[c], s);
        atomicAdd(&bn[16 + c], s2);
    }
}

// ---------------- BN apply + log_softmax + out (dtype-branched) ----------------

__global__ __launch_bounds__(256) void k_final(
    const float* __restrict__ logits, const float* __restrict__ bn,
    const float* __restrict__ gamma, const float* __restrict__ beta,
    const void* __restrict__ x1, void* __restrict__ out, int N)
{
    int f = detect_bf16(x1);
    int r = blockIdx.x * blockDim.x + threadIdx.x;
    if (r >= N) return;
    float invN = 1.f / (float)N;
    float y[16];
    float mx = -1e30f;
    #pragma unroll
    for (int c = 0; c < 16; c++) {
        float mu = bn[c] * invN;
        float var = bn[16 + c] * invN - mu * mu;
        float v = (logits[r * 16 + c] - mu) * rsqrtf(var + 1e-5f);
        v = v * gamma[c] + beta[c];
        y[c] = v;
        mx = fmaxf(mx, v);
    }
    float se = 0.f;
    #pragma unroll
    for (int c = 0; c < 16; c++) se += __expf(y[c] - mx);
    float lse = mx + __logf(se);
    #pragma unroll
    for (int c = 0; c < 16; c++) {
        float v = y[c] - lse;
        if (f) ((__hip_bfloat16*)out)[r * 16 + c] = __float2bfloat16(v);
        else   ((float*)out)[r * 16 + c] = v;
    }
}

// ---------------- launch ----------------

extern "C" void kernel_launch(void* const* d_in, const int* in_sizes, int n_in,
                              void* d_out, int out_size, void* d_ws, size_t ws_size,
                              hipStream_t stream) {
    const void* x1  = d_in[0];
    const void* x2  = d_in[1];
    const int*  ei1 = (const int*)d_in[2];
    const int*  ei2 = (const int*)d_in[3];

    const int N = in_sizes[0] / 64;
    const int E = in_sizes[2] / 2;
    const int nb = (N + 255) >> 8;          // buckets per graph

    char* p = (char*)d_ws;
    auto alloc = [&](size_t bytes) {
        void* q = (void*)p;
        p += (bytes + 255) & ~(size_t)255;
        return q;
    };
    // zero region: bfill1, bfill2, bn (single small memset)
    char* zbase   = (char*)alloc(0);
    int* bfill1   = (int*)alloc((size_t)nb * 4);
    int* bfill2   = (int*)alloc((size_t)nb * 4);
    float* bn     = (float*)alloc(256);
    size_t zbytes = (size_t)((char*)alloc(0) - zbase);

    float* h0     = (float*)alloc((size_t)N * 64 * 4);   // 25.6 MB
    float* h1     = (float*)alloc((size_t)N * 64 * 4);   // 25.6 MB
    float* hlin   = (float*)alloc((size_t)N * 64 * 4);
    float* as_    = (float*)alloc((size_t)N * 4);
    float* ad_    = (float*)alloc((size_t)N * 4);
    int* rowptr1  = (int*)alloc((size_t)N * 4);
    int* deg1     = (int*)alloc((size_t)N * 4);
    int* rowptr2  = (int*)alloc((size_t)N * 4);
    int* deg2     = (int*)alloc((size_t)N * 4);
    int* col1     = (int*)alloc((size_t)nb * CAP * 4);   // padded CSR; aliased as logits later
    int* col2     = (int*)alloc((size_t)nb * CAP * 4);
    float* P      = (float*)alloc(P_TOTAL * 4);
    float* logits = (float*)col1;  // col1 dead after layer-0 agg; nb*CAP*4 >= N*16*4

    // bedge buffers alias h0/h1: dead before first h write (gemm0 writes hlin,
    // agg0 writes h0, both strictly after k_bucket2).
    int2* bedge1  = (int2*)h0;                                   // nb*CAP*8 = 19.2 MB
    int2* bedge2  = (int2*)((char*)h0 + (size_t)nb * CAP * 8);   // spills into h1 region

    hipMemsetAsync(zbase, 0, zbytes, stream);

    const int TB = 256;
    int gN = (N + TB - 1) / TB;
    int gW = (N + 3) / 4;

    Ptrs15 pp;
    pp.p[0] = d_in[4];  pp.p[1] = d_in[8];   pp.p[2] = d_in[12];
    pp.p[3] = d_in[5];  pp.p[4] = d_in[6];   pp.p[5] = d_in[7];
    pp.p[6] = d_in[9];  pp.p[7] = d_in[10];  pp.p[8] = d_in[11];
    pp.p[9] = d_in[13]; pp.p[10] = d_in[14]; pp.p[11] = d_in[15];
    pp.p[12] = d_in[16]; pp.p[13] = d_in[17]; pp.p[14] = x1;
    k_params<<<14, 256, 0, stream>>>(pp, P);

    // CSR build: bucket scatter + per-bucket LDS count/scan/scatter
    k_scatter<<<1024, TB, 0, stream>>>(ei1, ei2, E, bfill1, bfill2, bedge1, bedge2);
    k_bucket2<<<2 * nb, TB, 0, stream>>>(bfill1, bedge1, rowptr1, deg1, col1,
                                         bfill2, bedge2, rowptr2, deg2, col2, nb, N);

    // Layer 0: x1 (raw) @ W0 -> hlin; aggregate graph1 -> h0 (elu)
    {
        int nt = (N + 63) / 64;
        k_gemm<64, 64, 64><<<(nt < 512 ? nt : 512), TB, 0, stream>>>(
            x1, x1, 1, P + P_W0, P + P_AS0, P + P_AD0, hlin, as_, ad_, N, nt);
    }
    k_agg64<<<gW, TB, 0, stream>>>(rowptr1, deg1, col1, as_, ad_, hlin, P + P_B0, h0, N, 1);

    // Layer 1: [h0 | x2(raw)] @ W1 -> hlin; aggregate graph2 -> h1 (elu)
    {
        int nt = (N + 31) / 32;
        k_gemm<128, 64, 32><<<(nt < 512 ? nt : 512), TB, 0, stream>>>(
            h0, x2, 2, P + P_W1, P + P_AS1, P + P_AD1, hlin, as_, ad_, N, nt);
    }
    k_agg64<<<gW, TB, 0, stream>>>(rowptr2, deg2, col2, as_, ad_, hlin, P + P_B1, h1, N, 1);

    // Layer 2: [h0 | h1] @ W2 -> hlin(:,:16); aggregate graph2 -> logits
    {
        int nt = (N + 63) / 64;
        k_gemm<128, 16, 64><<<(nt < 512 ? nt : 512), TB, 0, stream>>>(
            h0, h1, 0, P + P_W2, P + P_AS2, P + P_AD2, hlin, as_, ad_, N, nt);
    }
    k_agg16<<<gW, TB, 0, stream>>>(rowptr2, deg2, col2, as_, ad_, hlin, P + P_B2, logits, N);

    // BN + log_softmax
    k_bnstat<<<256, TB, 0, stream>>>(logits, bn, N);
    k_final<<<gN, TB, 0, stream>>>(logits, bn, P + P_GAMMA, P + P_BETA, x1, d_out, N);
}

// Round 6
// 638.062 us; speedup vs baseline: 2.4332x; 2.4332x over previous
//
#include <hip/hip_runtime.h>
#include <hip/hip_bf16.h>

#define DEV __device__ __forceinline__

DEV float bf2f(__hip_bfloat16 v) { return __bfloat162float(v); }
DEV float lrelu(float x) { return x > 0.f ? x : 0.2f * x; }
DEV float eluf(float x) { return x > 0.f ? x : (__expf(x) - 1.f); }

// Read element i of a float tensor that is either bf16 (f=1) or fp32 (f=0).
DEV float ldf(const void* p, int i, int f) {
    return f ? bf2f(((const __hip_bfloat16*)p)[i]) : ((const float*)p)[i];
}

// Inline dtype detection (see r2 notes): bf16 low-half exponent test, 64 samples.
DEV int detect_bf16(const void* p) {
    const unsigned int* w = (const unsigned int*)p;
    unsigned int e = (w[threadIdx.x & 63] >> 7) & 0xFFu;
    int hit = (e >= 112u && e <= 130u) ? 1 : 0;
    unsigned long long b = __ballot(hit);
    return __popcll(b) > 32 ? 1 : 0;
}

// ---------------- param conversion ----------------

struct Ptrs15 { const void* p[15]; };  // [14] = x1 (for detection)

#define P_W0 0
#define P_W1 4096
#define P_W2 12288
#define P_AS0 14336
#define P_AD0 14400
#define P_B0 14464
#define P_AS1 14528
#define P_AD1 14592
#define P_B1 14656
#define P_AS2 14720
#define P_AD2 14736
#define P_B2 14752
#define P_GAMMA 14768
#define P_BETA 14784
#define P_TOTAL 14800

__global__ void k_params(Ptrs15 pp, float* __restrict__ P) {
    const int narr[14] = {4096, 8192, 2048, 64, 64, 64, 64, 64, 64, 16, 16, 16, 16, 16};
    const int oarr[14] = {P_W0, P_W1, P_W2, P_AS0, P_AD0, P_B0, P_AS1, P_AD1, P_B1,
                          P_AS2, P_AD2, P_B2, P_GAMMA, P_BETA};
    int f = detect_bf16(pp.p[14]);
    int b = blockIdx.x;
    const void* src = pp.p[b];
    int nn = narr[b], oo = oarr[b];
    for (int i = threadIdx.x; i < nn; i += blockDim.x)
        P[oo + i] = ldf(src, i, f);
}

// ---------------- CSR build: contention-free 3-phase bucket sort ----------------
// Bucket = dst >> 8 (256 nodes). NB = buckets over BOTH graphs (graph2 offset nb).
// counts matrix is bucket-major: counts[b * NBLK + blk].
// No contended global atomics anywhere (r5 lesson: same-address atomic ~240ns).

#define CAP 6144
#define NBLK 512
#define NBMAX 1024

__global__ __launch_bounds__(256) void k_count(
    const int* __restrict__ ei1, const int* __restrict__ ei2, int E,
    int* __restrict__ counts, int nb, int NB, int chunk)
{
    __shared__ int lcnt[NBMAX];
    int t = threadIdx.x, blk = blockIdx.x;
    for (int b = t; b < NB; b += 256) lcnt[b] = 0;
    __syncthreads();
    int i0 = blk * chunk, i1 = min(i0 + chunk, 2 * E);
    for (int i = i0 + t; i < i1; i += 256) {
        int b;
        if (i < E) b = ei1[E + i] >> 8;
        else       b = (ei2[i] >> 8) + nb;   // ei2[E + (i-E)]
        atomicAdd(&lcnt[b], 1);
    }
    __syncthreads();
    for (int b = t; b < NB; b += 256) counts[b * NBLK + blk] = lcnt[b];
}

// One block per bucket: exclusive scan of its 512 block-counts; writes bases
// back in place and the bucket total to bfill[b].
__global__ __launch_bounds__(256) void k_scan(
    int* __restrict__ counts, int* __restrict__ bfill)
{
    int b = blockIdx.x, t = threadIdx.x;
    __shared__ int ps[256];
    int* row = counts + b * NBLK;
    int x0 = row[2 * t], x1 = row[2 * t + 1];
    ps[t] = x0 + x1;
    __syncthreads();
    #pragma unroll
    for (int off = 1; off < 256; off <<= 1) {
        int v = (t >= off) ? ps[t - off] : 0;
        __syncthreads();
        ps[t] += v;
        __syncthreads();
    }
    int excl = ps[t] - (x0 + x1);          // exclusive over pairs
    row[2 * t] = excl;
    row[2 * t + 1] = excl + x0;
    if (t == 255) bfill[b] = ps[255];
}

__global__ __launch_bounds__(256) void k_place(
    const int* __restrict__ ei1, const int* __restrict__ ei2, int E,
    const int* __restrict__ counts, int2* __restrict__ bedge,
    int nb, int NB, int chunk)
{
    __shared__ int lbase[NBMAX];
    int t = threadIdx.x, blk = blockIdx.x;
    for (int b = t; b < NB; b += 256) lbase[b] = counts[b * NBLK + blk];
    __syncthreads();
    int i0 = blk * chunk, i1 = min(i0 + chunk, 2 * E);
    for (int i = i0 + t; i < i1; i += 256) {
        int s, d, b;
        if (i < E) { s = ei1[i]; d = ei1[E + i]; b = d >> 8; }
        else       { s = ei2[i - E]; d = ei2[i]; b = (d >> 8) + nb; }
        int pos = atomicAdd(&lbase[b], 1);
        if (pos < CAP) bedge[(size_t)b * CAP + pos] = make_int2(s, d);
    }
}

// One block per bucket: LDS degree count + scan + scatter into a contiguous,
// L2-resident window of the padded col array. Writes rowptr/deg too.
__global__ __launch_bounds__(256) void k_bucket2(
    const int* __restrict__ bfill1, const int2* __restrict__ bedge1,
    int* __restrict__ rp1, int* __restrict__ dg1, int* __restrict__ col1,
    const int* __restrict__ bfill2, const int2* __restrict__ bedge2,
    int* __restrict__ rp2, int* __restrict__ dg2, int* __restrict__ col2,
    int nb, int N)
{
    int b = blockIdx.x;
    const int* bfill; const int2* bedge; int* rowptr; int* deg; int* col;
    if (b < nb) { bfill = bfill1; bedge = bedge1; rowptr = rp1; deg = dg1; col = col1; }
    else { b -= nb; bfill = bfill2; bedge = bedge2; rowptr = rp2; deg = dg2; col = col2; }

    __shared__ int ldeg[256], lscan[256], lfill[256];
    int t = threadIdx.x;
    ldeg[t] = 0;
    __syncthreads();

    int cnt = min(bfill[b], CAP);
    const int2* be = bedge + (size_t)b * CAP;
    for (int e = t; e < cnt; e += 256) atomicAdd(&ldeg[be[e].y & 255], 1);
    __syncthreads();

    int myDeg = ldeg[t];
    lscan[t] = myDeg;
    __syncthreads();
    #pragma unroll
    for (int off = 1; off < 256; off <<= 1) {
        int v = (t >= off) ? lscan[t - off] : 0;
        __syncthreads();
        lscan[t] += v;
        __syncthreads();
    }
    int excl = lscan[t] - myDeg;
    int node = (b << 8) + t;
    int base = b * CAP;
    if (node < N) { rowptr[node] = base + excl; deg[node] = myDeg; }
    lfill[t] = excl;
    __syncthreads();

    for (int e = t; e < cnt; e += 256) {
        int2 ed = be[e];
        int pos = atomicAdd(&lfill[ed.y & 255], 1);
        col[base + pos] = ed.x;
    }
}

// ---------------- persistent templated GEMM (unchanged from r3) ----------------

template <int K, int C, int TR>
__global__ __launch_bounds__(256) void k_gemm(
    const void* __restrict__ A1, const void* __restrict__ A2, int rawMask,
    const float* __restrict__ W, const float* __restrict__ av, const float* __restrict__ dv,
    float* __restrict__ Hout, float* __restrict__ as_, float* __restrict__ ad_,
    int N, int numTiles)
{
    constexpr int CQ = C / 4;
    constexpr int RG = 256 / CQ;
    constexpr int RPT = TR / RG;
    constexpr int PADR = TR + 1;
    __shared__ float Ws[K * C];
    __shared__ float xs[K * PADR];

    int f = 0;
    if (rawMask) f = detect_bf16((rawMask & 1) ? A1 : A2);

    int t = threadIdx.x;
    for (int idx = t; idx < K * C; idx += 256) Ws[idx] = W[idx];

    const int cq = t % CQ, rg = t / CQ;

    for (int tile = blockIdx.x; tile < numTiles; tile += gridDim.x) {
        int rowBase = tile * TR;
        for (int idx = t; idx < K * TR; idx += 256) {
            int rr = idx / K, k = idx % K;
            int row = rowBase + rr;
            float v = 0.f;
            if (row < N) {
                if (k < 64) v = (rawMask & 1) ? ldf(A1, row * 64 + k, f)
                                              : ((const float*)A1)[row * 64 + k];
                else        v = (rawMask & 2) ? ldf(A2, row * 64 + (k - 64), f)
                                              : ((const float*)A2)[row * 64 + (k - 64)];
            }
            xs[k * PADR + rr] = v;
        }
        __syncthreads();

        float acc[RPT][4];
        #pragma unroll
        for (int r = 0; r < RPT; r++)
            for (int c = 0; c < 4; c++) acc[r][c] = 0.f;

        #pragma unroll 4
        for (int k = 0; k < K; k++) {
            float4 wv = *(const float4*)&Ws[k * C + cq * 4];
            #pragma unroll
            for (int r = 0; r < RPT; r++) {
                float xv = xs[k * PADR + rg * RPT + r];
                acc[r][0] += xv * wv.x;
                acc[r][1] += xv * wv.y;
                acc[r][2] += xv * wv.z;
                acc[r][3] += xv * wv.w;
            }
        }

        #pragma unroll
        for (int r = 0; r < RPT; r++) {
            int row = rowBase + rg * RPT + r;
            float4 o = {acc[r][0], acc[r][1], acc[r][2], acc[r][3]};
            float a0 = av[cq * 4], a1 = av[cq * 4 + 1], a2 = av[cq * 4 + 2], a3 = av[cq * 4 + 3];
            float d0 = dv[cq * 4], d1 = dv[cq * 4 + 1], d2 = dv[cq * 4 + 2], d3 = dv[cq * 4 + 3];
            float vs = o.x * a0 + o.y * a1 + o.z * a2 + o.w * a3;
            float vd = o.x * d0 + o.y * d1 + o.z * d2 + o.w * d3;
            #pragma unroll
            for (int off = CQ >> 1; off; off >>= 1) {
                vs += __shfl_xor(vs, off);
                vd += __shfl_xor(vd, off);
            }
            if (row < N) {
                *(float4*)&Hout[(size_t)row * C + cq * 4] = o;
                if (cq == 0) { as_[row] = vs; ad_[row] = vd; }
            }
        }
        __syncthreads();
    }
}

// ---------------- Aggregation F=64 (unchanged from r3) ----------------

__global__ __launch_bounds__(256) void k_agg64(
    const int* __restrict__ rowptr, const int* __restrict__ deg,
    const int* __restrict__ col, const float* __restrict__ as_,
    const float* __restrict__ ad_, const float* __restrict__ h,
    const float* __restrict__ bias, float* __restrict__ out,
    int N, int doElu)
{
    int wid = (blockIdx.x * blockDim.x + threadIdx.x) >> 6;
    int lane = threadIdx.x & 63;
    if (wid >= N) return;
    int start = rowptr[wid];
    int d = deg[wid];
    float adi = ad_[wid];
    float eself = __expf(lrelu(as_[wid] + adi));

    int dc = min(d, 64);
    float w = 0.f; int s = 0;
    if (lane < dc) { s = col[start + lane]; w = __expf(lrelu(as_[s] + adi)); }
    float ssum = w;
    for (int j = lane + 64; j < d; j += 64)
        ssum += __expf(lrelu(as_[col[start + j]] + adi));
    #pragma unroll
    for (int off = 32; off; off >>= 1) ssum += __shfl_xor(ssum, off);
    float inv = 1.f / (ssum + eself + 1e-16f);
    w *= inv;

    int fq = lane & 15, eg = lane >> 4;
    const float4* h4 = (const float4*)h;
    float4 acc = {0.f, 0.f, 0.f, 0.f};
    if (eg == 0) {
        float4 hv = h4[(size_t)wid * 16 + fq];
        float en = eself * inv;
        acc.x = en * hv.x; acc.y = en * hv.y; acc.z = en * hv.z; acc.w = en * hv.w;
    }
    {
        int iters = (dc + 3) >> 2;
        for (int it = 0; it < iters; it++) {
            int j = it * 4 + eg;
            float wj = __shfl(w, j);
            int sj = __shfl(s, j);
            if (j < dc) {
                float4 hv = h4[(size_t)sj * 16 + fq];
                acc.x += wj * hv.x; acc.y += wj * hv.y;
                acc.z += wj * hv.z; acc.w += wj * hv.w;
            }
        }
    }
    for (int base = 64; base < d; base += 64) {
        int cnt = min(64, d - base);
        float w2 = 0.f; int s2 = 0;
        if (lane < cnt) { s2 = col[start + base + lane]; w2 = __expf(lrelu(as_[s2] + adi)) * inv; }
        int iters = (cnt + 3) >> 2;
        for (int it = 0; it < iters; it++) {
            int j = it * 4 + eg;
            float wj = __shfl(w2, j);
            int sj = __shfl(s2, j);
            if (j < cnt) {
                float4 hv = h4[(size_t)sj * 16 + fq];
                acc.x += wj * hv.x; acc.y += wj * hv.y;
                acc.z += wj * hv.z; acc.w += wj * hv.w;
            }
        }
    }
    #pragma unroll
    for (int off = 16; off < 64; off <<= 1) {
        acc.x += __shfl_xor(acc.x, off);
        acc.y += __shfl_xor(acc.y, off);
        acc.z += __shfl_xor(acc.z, off);
        acc.w += __shfl_xor(acc.w, off);
    }
    if (lane < 16) {
        float4 b4 = ((const float4*)bias)[lane];
        float4 o = {acc.x + b4.x, acc.y + b4.y, acc.z + b4.z, acc.w + b4.w};
        if (doElu) { o.x = eluf(o.x); o.y = eluf(o.y); o.z = eluf(o.z); o.w = eluf(o.w); }
        ((float4*)out)[(size_t)wid * 16 + lane] = o;
    }
}

// ---------------- Aggregation F=16 (unchanged from r3) ----------------

__global__ __launch_bounds__(256) void k_agg16(
    const int* __restrict__ rowptr, const int* __restrict__ deg,
    const int* __restrict__ col, const float* __restrict__ as_,
    const float* __restrict__ ad_, const float* __restrict__ h,
    const float* __restrict__ bias, float* __restrict__ out, int N)
{
    int wid = (blockIdx.x * blockDim.x + threadIdx.x) >> 6;
    int lane = threadIdx.x & 63;
    if (wid >= N) return;
    int start = rowptr[wid];
    int d = deg[wid];
    float adi = ad_[wid];
    float eself = __expf(lrelu(as_[wid] + adi));

    int dc = min(d, 64);
    float w = 0.f; int s = 0;
    if (lane < dc) { s = col[start + lane]; w = __expf(lrelu(as_[s] + adi)); }
    float ssum = w;
    for (int j = lane + 64; j < d; j += 64)
        ssum += __expf(lrelu(as_[col[start + j]] + adi));
    #pragma unroll
    for (int off = 32; off; off >>= 1) ssum += __shfl_xor(ssum, off);
    float inv = 1.f / (ssum + eself + 1e-16f);
    w *= inv;

    int fq = lane & 3, eg = lane >> 2;
    const float4* h4 = (const float4*)h;
    float4 acc = {0.f, 0.f, 0.f, 0.f};
    if (eg == 0) {
        float4 hv = h4[(size_t)wid * 4 + fq];
        float en = eself * inv;
        acc.x = en * hv.x; acc.y = en * hv.y; acc.z = en * hv.z; acc.w = en * hv.w;
    }
    {
        int iters = (dc + 15) >> 4;
        for (int it = 0; it < iters; it++) {
            int j = it * 16 + eg;
            float wj = __shfl(w, j);
            int sj = __shfl(s, j);
            if (j < dc) {
                float4 hv = h4[(size_t)sj * 4 + fq];
                acc.x += wj * hv.x; acc.y += wj * hv.y;
                acc.z += wj * hv.z; acc.w += wj * hv.w;
            }
        }
    }
    for (int base = 64; base < d; base += 64) {
        int cnt = min(64, d - base);
        float w2 = 0.f; int s2 = 0;
        if (lane < cnt) { s2 = col[start + base + lane]; w2 = __expf(lrelu(as_[s2] + adi)) * inv; }
        int iters = (cnt + 15) >> 4;
        for (int it = 0; it < iters; it++) {
            int j = it * 16 + eg;
            float wj = __shfl(w2, j);
            int sj = __shfl(s2, j);
            if (j < cnt) {
                float4 hv = h4[(size_t)sj * 4 + fq];
                acc.x += wj * hv.x; acc.y += wj * hv.y;
                acc.z += wj * hv.z; acc.w += wj * hv.w;
            }
        }
    }
    #pragma unroll
    for (int off = 4; off < 64; off <<= 1) {
        acc.x += __shfl_xor(acc.x, off);
        acc.y += __shfl_xor(acc.y, off);
        acc.z += __shfl_xor(acc.z, off);
        acc.w += __shfl_xor(acc.w, off);
    }
    if (lane < 4) {
        float4 b4 = ((const float4*)bias)[lane];
        float4 o = {acc.x + b4.x, acc.y + b4.y, acc.z + b4.z, acc.w + b4.w};
        ((float4*)out)[(size_t)wid * 4 + lane] = o;
    }
}

// ---------------- BatchNorm stats ----------------

__global__ __launch_bounds__(256) void k_bnstat(const float* __restrict__ logits,
                                                float* __restrict__ bn, int N) {
    int t = threadIdx.x;
    int c = t & 15;
    int g = (blockIdx.x * blockDim.x + t) >> 4;
    int stride = (gridDim.x * blockDim.x) >> 4;
    float s = 0.f, s2 = 0.f;
    for (int r = g; r < N; r += stride) {
        float v = logits[r * 16 + c];
        s += v;
        s2 += v * v;
    }
    s += __shfl_xor(s, 16);  s += __shfl_xor(s, 32);
    s2 += __shfl_xor(s2, 16); s2 += __shfl_xor(s2, 32);
    if ((t & 63) < 16) {
        atomicAdd(&bn[c], s);
        atomicAdd(&bn[16 + c], s2);
    }
}

// ---------------- BN apply + log_softmax + out (dtype-branched) ----------------

__global__ __launch_bounds__(256) void k_final(
    const float* __restrict__ logits, const float* __restrict__ bn,
    const float* __restrict__ gamma, const float* __restrict__ beta,
    const void* __restrict__ x1, void* __restrict__ out, int N)
{
    int f = detect_bf16(x1);
    int r = blockIdx.x * blockDim.x + threadIdx.x;
    if (r >= N) return;
    float invN = 1.f / (float)N;
    float y[16];
    float mx = -1e30f;
    #pragma unroll
    for (int c = 0; c < 16; c++) {
        float mu = bn[c] * invN;
        float var = bn[16 + c] * invN - mu * mu;
        float v = (logits[r * 16 + c] - mu) * rsqrtf(var + 1e-5f);
        v = v * gamma[c] + beta[c];
        y[c] = v;
        mx = fmaxf(mx, v);
    }
    float se = 0.f;
    #pragma unroll
    for (int c = 0; c < 16; c++) se += __expf(y[c] - mx);
    float lse = mx + __logf(se);
    #pragma unroll
    for (int c = 0; c < 16; c++) {
        float v = y[c] - lse;
        if (f) ((__hip_bfloat16*)out)[r * 16 + c] = __float2bfloat16(v);
        else   ((float*)out)[r * 16 + c] = v;
    }
}

// ---------------- launch ----------------

extern "C" void kernel_launch(void* const* d_in, const int* in_sizes, int n_in,
                              void* d_out, int out_size, void* d_ws, size_t ws_size,
                              hipStream_t stream) {
    const void* x1  = d_in[0];
    const void* x2  = d_in[1];
    const int*  ei1 = (const int*)d_in[2];
    const int*  ei2 = (const int*)d_in[3];

    const int N = in_sizes[0] / 64;
    const int E = in_sizes[2] / 2;
    const int nb = (N + 255) >> 8;          // buckets per graph
    const int NB = 2 * nb;                  // both graphs
    const int chunk = (2 * E + NBLK - 1) / NBLK;

    char* p = (char*)d_ws;
    auto alloc = [&](size_t bytes) {
        void* q = (void*)p;
        p += (bytes + 255) & ~(size_t)255;
        return q;
    };
    float* bn     = (float*)alloc(256);                  // zeroed by memset
    float* h0     = (float*)alloc((size_t)N * 64 * 4);   // 25.6 MB
    float* h1     = (float*)alloc((size_t)N * 64 * 4);   // 25.6 MB
    float* hlin   = (float*)alloc((size_t)N * 64 * 4);
    float* as_    = (float*)alloc((size_t)N * 4);
    float* ad_    = (float*)alloc((size_t)N * 4);
    int* rowptr1  = (int*)alloc((size_t)N * 4);
    int* deg1     = (int*)alloc((size_t)N * 4);
    int* rowptr2  = (int*)alloc((size_t)N * 4);
    int* deg2     = (int*)alloc((size_t)N * 4);
    int* col1     = (int*)alloc((size_t)nb * CAP * 4);   // padded CSR; aliased as logits later
    int* col2     = (int*)alloc((size_t)nb * CAP * 4);
    int* counts   = (int*)alloc((size_t)NB * NBLK * 4);  // bucket-major count/base matrix
    int* bfill    = (int*)alloc((size_t)NB * 4);         // per-bucket totals (from k_scan)
    float* P      = (float*)alloc(P_TOTAL * 4);
    float* logits = (float*)col1;  // col1 dead after layer-0 agg; nb*CAP*4 >= N*16*4

    // bedge aliases h0/h1: dead before first h write (gemm0 writes hlin,
    // agg0 writes h0, both strictly after k_bucket2). NB*CAP*8 = 38.4 MB <= 51.2 MB.
    int2* bedge   = (int2*)h0;
    int2* bedge2p = bedge + (size_t)nb * CAP;

    hipMemsetAsync(bn, 0, 256, stream);

    const int TB = 256;
    int gN = (N + TB - 1) / TB;
    int gW = (N + 3) / 4;

    Ptrs15 pp;
    pp.p[0] = d_in[4];  pp.p[1] = d_in[8];   pp.p[2] = d_in[12];
    pp.p[3] = d_in[5];  pp.p[4] = d_in[6];   pp.p[5] = d_in[7];
    pp.p[6] = d_in[9];  pp.p[7] = d_in[10];  pp.p[8] = d_in[11];
    pp.p[9] = d_in[13]; pp.p[10] = d_in[14]; pp.p[11] = d_in[15];
    pp.p[12] = d_in[16]; pp.p[13] = d_in[17]; pp.p[14] = x1;
    k_params<<<14, 256, 0, stream>>>(pp, P);

    // CSR build: count -> scan -> place -> per-bucket node sort
    k_count<<<NBLK, TB, 0, stream>>>(ei1, ei2, E, counts, nb, NB, chunk);
    k_scan<<<NB, TB, 0, stream>>>(counts, bfill);
    k_place<<<NBLK, TB, 0, stream>>>(ei1, ei2, E, counts, bedge, nb, NB, chunk);
    k_bucket2<<<NB, TB, 0, stream>>>(bfill, bedge, rowptr1, deg1, col1,
                                     bfill + nb, bedge2p, rowptr2, deg2, col2, nb, N);

    // Layer 0: x1 (raw) @ W0 -> hlin; aggregate graph1 -> h0 (elu)
    {
        int nt = (N + 63) / 64;
        k_gemm<64, 64, 64><<<(nt < 512 ? nt : 512), TB, 0, stream>>>(
            x1, x1, 1, P + P_W0, P + P_AS0, P + P_AD0, hlin, as_, ad_, N, nt);
    }
    k_agg64<<<gW, TB, 0, stream>>>(rowptr1, deg1, col1, as_, ad_, hlin, P + P_B0, h0, N, 1);

    // Layer 1: [h0 | x2(raw)] @ W1 -> hlin; aggregate graph2 -> h1 (elu)
    {
        int nt = (N + 31) / 32;
        k_gemm<128, 64, 32><<<(nt < 512 ? nt : 512), TB, 0, stream>>>(
            h0, x2, 2, P + P_W1, P + P_AS1, P + P_AD1, hlin, as_, ad_, N, nt);
    }
    k_agg64<<<gW, TB, 0, stream>>>(rowptr2, deg2, col2, as_, ad_, hlin, P + P_B1, h1, N, 1);

    // Layer 2: [h0 | h1] @ W2 -> hlin(:,:16); aggregate graph2 -> logits
    {
        int nt = (N + 63) / 64;
        k_gemm<128, 16, 64><<<(nt < 512 ? nt : 512), TB, 0, stream>>>(
            h0, h1, 0, P + P_W2, P + P_AS2, P + P_AD2, hlin, as_, ad_, N, nt);
    }
    k_agg16<<<gW, TB, 0, stream>>>(rowptr2, deg2, col2, as_, ad_, hlin, P + P_B2, logits, N);

    // BN + log_softmax
    k_bnstat<<<256, TB, 0, stream>>>(logits, bn, N);
    k_final<<<gN, TB, 0, stream>>>(logits, bn, P + P_GAMMA, P + P_BETA, x1, d_out, N);
}

// Round 7
// 492.191 us; speedup vs baseline: 3.1543x; 1.2964x over previous
//
#include <hip/hip_runtime.h>
#include <hip/hip_bf16.h>

#define DEV __device__ __forceinline__

typedef __attribute__((ext_vector_type(8))) short bf16x8;
typedef __attribute__((ext_vector_type(4))) float f32x4;

DEV float bf2f(__hip_bfloat16 v) { return __bfloat162float(v); }
DEV float lrelu(float x) { return x > 0.f ? x : 0.2f * x; }
DEV float eluf(float x) { return x > 0.f ? x : (__expf(x) - 1.f); }

// fp32 -> bf16 bits, round-to-nearest-even
DEV unsigned short f2bf(float x) {
    unsigned int u = __float_as_uint(x);
    return (unsigned short)((u + 0x7FFFu + ((u >> 16) & 1u)) >> 16);
}

// Read element i of a float tensor that is either bf16 (f=1) or fp32 (f=0).
DEV float ldf(const void* p, int i, int f) {
    return f ? bf2f(((const __hip_bfloat16*)p)[i]) : ((const float*)p)[i];
}

// Inline dtype detection (see r2 notes): bf16 low-half exponent test, 64 samples.
DEV int detect_bf16(const void* p) {
    const unsigned int* w = (const unsigned int*)p;
    unsigned int e = (w[threadIdx.x & 63] >> 7) & 0xFFu;
    int hit = (e >= 112u && e <= 130u) ? 1 : 0;
    unsigned long long b = __ballot(hit);
    return __popcll(b) > 32 ? 1 : 0;
}

// Load 8 consecutive "float" elems as 8 packed bf16 (16B).
// mode==0: src is our own bf16 buffer. mode==1: raw input, branch on f.
DEV uint4 ld8(const void* src, size_t off, int mode, int f) {
    if (mode == 0 || f) return *(const uint4*)((const unsigned short*)src + off);
    const float* s = (const float*)src + off;
    float4 a = *(const float4*)s, b = *(const float4*)(s + 4);
    uint4 r;
    r.x = f2bf(a.x) | ((unsigned)f2bf(a.y) << 16);
    r.y = f2bf(a.z) | ((unsigned)f2bf(a.w) << 16);
    r.z = f2bf(b.x) | ((unsigned)f2bf(b.y) << 16);
    r.w = f2bf(b.z) | ((unsigned)f2bf(b.w) << 16);
    return r;
}

// ---------------- param conversion ----------------

struct Ptrs15 { const void* p[15]; };  // [14] = x1 (for detection)

#define P_W0 0
#define P_W1 4096
#define P_W2 12288
#define P_AS0 14336
#define P_AD0 14400
#define P_B0 14464
#define P_AS1 14528
#define P_AD1 14592
#define P_B1 14656
#define P_AS2 14720
#define P_AD2 14736
#define P_B2 14752
#define P_GAMMA 14768
#define P_BETA 14784
#define P_TOTAL 14800

__global__ void k_params(Ptrs15 pp, float* __restrict__ P) {
    const int narr[14] = {4096, 8192, 2048, 64, 64, 64, 64, 64, 64, 16, 16, 16, 16, 16};
    const int oarr[14] = {P_W0, P_W1, P_W2, P_AS0, P_AD0, P_B0, P_AS1, P_AD1, P_B1,
                          P_AS2, P_AD2, P_B2, P_GAMMA, P_BETA};
    int f = detect_bf16(pp.p[14]);
    int b = blockIdx.x;
    const void* src = pp.p[b];
    int nn = narr[b], oo = oarr[b];
    for (int i = threadIdx.x; i < nn; i += blockDim.x)
        P[oo + i] = ldf(src, i, f);
}

// ---------------- CSR build: contention-free 3-phase bucket sort (r6) ----------------

#define CAP 6144
#define NBLK 512
#define NBMAX 1024

__global__ __launch_bounds__(256) void k_count(
    const int* __restrict__ ei1, const int* __restrict__ ei2, int E,
    int* __restrict__ counts, int nb, int NB, int chunk)
{
    __shared__ int lcnt[NBMAX];
    int t = threadIdx.x, blk = blockIdx.x;
    for (int b = t; b < NB; b += 256) lcnt[b] = 0;
    __syncthreads();
    int i0 = blk * chunk, i1 = min(i0 + chunk, 2 * E);
    for (int i = i0 + t; i < i1; i += 256) {
        int b;
        if (i < E) b = ei1[E + i] >> 8;
        else       b = (ei2[i] >> 8) + nb;
        atomicAdd(&lcnt[b], 1);
    }
    __syncthreads();
    for (int b = t; b < NB; b += 256) counts[b * NBLK + blk] = lcnt[b];
}

__global__ __launch_bounds__(256) void k_scan(
    int* __restrict__ counts, int* __restrict__ bfill)
{
    int b = blockIdx.x, t = threadIdx.x;
    __shared__ int ps[256];
    int* row = counts + b * NBLK;
    int x0 = row[2 * t], x1 = row[2 * t + 1];
    ps[t] = x0 + x1;
    __syncthreads();
    #pragma unroll
    for (int off = 1; off < 256; off <<= 1) {
        int v = (t >= off) ? ps[t - off] : 0;
        __syncthreads();
        ps[t] += v;
        __syncthreads();
    }
    int excl = ps[t] - (x0 + x1);
    row[2 * t] = excl;
    row[2 * t + 1] = excl + x0;
    if (t == 255) bfill[b] = ps[255];
}

__global__ __launch_bounds__(256) void k_place(
    const int* __restrict__ ei1, const int* __restrict__ ei2, int E,
    const int* __restrict__ counts, int2* __restrict__ bedge,
    int nb, int NB, int chunk)
{
    __shared__ int lbase[NBMAX];
    int t = threadIdx.x, blk = blockIdx.x;
    for (int b = t; b < NB; b += 256) lbase[b] = counts[b * NBLK + blk];
    __syncthreads();
    int i0 = blk * chunk, i1 = min(i0 + chunk, 2 * E);
    for (int i = i0 + t; i < i1; i += 256) {
        int s, d, b;
        if (i < E) { s = ei1[i]; d = ei1[E + i]; b = d >> 8; }
        else       { s = ei2[i - E]; d = ei2[i]; b = (d >> 8) + nb; }
        int pos = atomicAdd(&lbase[b], 1);
        if (pos < CAP) bedge[(size_t)b * CAP + pos] = make_int2(s, d);
    }
}

__global__ __launch_bounds__(256) void k_bucket2(
    const int* __restrict__ bfill1, const int2* __restrict__ bedge1,
    int* __restrict__ rp1, int* __restrict__ dg1, int* __restrict__ col1,
    const int* __restrict__ bfill2, const int2* __restrict__ bedge2,
    int* __restrict__ rp2, int* __restrict__ dg2, int* __restrict__ col2,
    int nb, int N)
{
    int b = blockIdx.x;
    const int* bfill; const int2* bedge; int* rowptr; int* deg; int* col;
    if (b < nb) { bfill = bfill1; bedge = bedge1; rowptr = rp1; deg = dg1; col = col1; }
    else { b -= nb; bfill = bfill2; bedge = bedge2; rowptr = rp2; deg = dg2; col = col2; }

    __shared__ int ldeg[256], lscan[256], lfill[256];
    int t = threadIdx.x;
    ldeg[t] = 0;
    __syncthreads();

    int cnt = min(bfill[b], CAP);
    const int2* be = bedge + (size_t)b * CAP;
    for (int e = t; e < cnt; e += 256) atomicAdd(&ldeg[be[e].y & 255], 1);
    __syncthreads();

    int myDeg = ldeg[t];
    lscan[t] = myDeg;
    __syncthreads();
    #pragma unroll
    for (int off = 1; off < 256; off <<= 1) {
        int v = (t >= off) ? lscan[t - off] : 0;
        __syncthreads();
        lscan[t] += v;
        __syncthreads();
    }
    int excl = lscan[t] - myDeg;
    int node = (b << 8) + t;
    int base = b * CAP;
    if (node < N) { rowptr[node] = base + excl; deg[node] = myDeg; }
    lfill[t] = excl;
    __syncthreads();

    for (int e = t; e < cnt; e += 256) {
        int2 ed = be[e];
        int pos = atomicAdd(&lfill[ed.y & 255], 1);
        col[base + pos] = ed.x;
    }
}

// ---------------- MFMA bf16 GEMM ----------------
// A = [A1(cols 0..63) | A2(cols 64..K-1)] bf16 (raw inputs dtype-branched),
// B = W (fp32 P buffer, transposed+converted to LDS once per block).
// 256 thr = 4 waves; tile = 64 rows x C cols; B-fragments hoisted to registers.
// Layouts (measured, m89/m120): A[m=lane&15][k=quad*8+j]; B[k=quad*8+j][n=lane&15];
// D col=lane&15, row=quad*4+reg.

template <int K, int C>
__global__ __launch_bounds__(256) void k_gemm_mfma(
    const void* __restrict__ A1, int mode1, const void* __restrict__ A2, int mode2,
    const float* __restrict__ W, const float* __restrict__ av, const float* __restrict__ dv,
    float* __restrict__ Hout, float* __restrict__ as_, float* __restrict__ ad_,
    int N, int numTiles)
{
    constexpr int KP = K + 8;     // padded row stride (shorts); 2-way LDS aliasing only
    constexpr int KK = K / 32;    // mfma k-steps
    constexpr int CT = C / 16;    // col tiles
    constexpr int G  = K / 8;     // 8-elem groups per A row

    __shared__ alignas(16) short As[64 * KP];
    __shared__ alignas(16) short Wt[C * KP];
    __shared__ float avs[C], dvs[C];

    int t = threadIdx.x;
    int f = 0;
    if (mode1) f = detect_bf16(A1);
    else if (mode2) f = detect_bf16(A2);

    for (int idx = t; idx < K * C; idx += 256) {
        int k = idx / C, n = idx % C;
        Wt[n * KP + k] = (short)f2bf(W[idx]);
    }
    for (int i = t; i < C; i += 256) { avs[i] = av[i]; dvs[i] = dv[i]; }
    __syncthreads();

    const int lane = t & 63, w = t >> 6;
    const int m = lane & 15, q = lane >> 4;

    bf16x8 bfr[KK][CT];
    #pragma unroll
    for (int kk = 0; kk < KK; kk++)
        #pragma unroll
        for (int ct = 0; ct < CT; ct++)
            bfr[kk][ct] = *(const bf16x8*)&Wt[(ct * 16 + m) * KP + kk * 32 + q * 8];

    for (int tile = blockIdx.x; tile < numTiles; tile += gridDim.x) {
        __syncthreads();
        int rowBase = tile * 64;
        for (int idx = t; idx < 64 * G; idx += 256) {
            int r = idx / G, g = idx % G;
            int row = rowBase + r;
            uint4 val = {0u, 0u, 0u, 0u};
            if (row < N) {
                if (g < 8) val = ld8(A1, (size_t)row * 64 + g * 8, mode1, f);
                else       val = ld8(A2, (size_t)row * 64 + (g - 8) * 8, mode2, f);
            }
            *(uint4*)&As[r * KP + g * 8] = val;
        }
        __syncthreads();

        f32x4 acc[CT];
        #pragma unroll
        for (int ct = 0; ct < CT; ct++) acc[ct] = (f32x4){0.f, 0.f, 0.f, 0.f};

        #pragma unroll
        for (int kk = 0; kk < KK; kk++) {
            bf16x8 a = *(const bf16x8*)&As[(w * 16 + m) * KP + kk * 32 + q * 8];
            #pragma unroll
            for (int ct = 0; ct < CT; ct++)
                acc[ct] = __builtin_amdgcn_mfma_f32_16x16x32_bf16(a, bfr[kk][ct], acc[ct], 0, 0, 0);
        }

        #pragma unroll
        for (int r = 0; r < 4; r++) {
            int grow = rowBase + w * 16 + q * 4 + r;
            float vs = 0.f, vd = 0.f;
            #pragma unroll
            for (int ct = 0; ct < CT; ct++) {
                float v = acc[ct][r];
                vs += v * avs[ct * 16 + m];
                vd += v * dvs[ct * 16 + m];
                if (grow < N) Hout[(size_t)grow * C + ct * 16 + m] = v;
            }
            vs += __shfl_xor(vs, 1); vs += __shfl_xor(vs, 2);
            vs += __shfl_xor(vs, 4); vs += __shfl_xor(vs, 8);
            vd += __shfl_xor(vd, 1); vd += __shfl_xor(vd, 2);
            vd += __shfl_xor(vd, 4); vd += __shfl_xor(vd, 8);
            if (grow < N && m == 0) { as_[grow] = vs; ad_[grow] = vd; }
        }
    }
}

// ---------------- Aggregation F=64: fused softmax; OUT IS BF16 now ----------------

__global__ __launch_bounds__(256) void k_agg64(
    const int* __restrict__ rowptr, const int* __restrict__ deg,
    const int* __restrict__ col, const float* __restrict__ as_,
    const float* __restrict__ ad_, const float* __restrict__ h,
    const float* __restrict__ bias, unsigned short* __restrict__ out,
    int N, int doElu)
{
    int wid = (blockIdx.x * blockDim.x + threadIdx.x) >> 6;
    int lane = threadIdx.x & 63;
    if (wid >= N) return;
    int start = rowptr[wid];
    int d = deg[wid];
    float adi = ad_[wid];
    float eself = __expf(lrelu(as_[wid] + adi));

    int dc = min(d, 64);
    float w = 0.f; int s = 0;
    if (lane < dc) { s = col[start + lane]; w = __expf(lrelu(as_[s] + adi)); }
    float ssum = w;
    for (int j = lane + 64; j < d; j += 64)
        ssum += __expf(lrelu(as_[col[start + j]] + adi));
    #pragma unroll
    for (int off = 32; off; off >>= 1) ssum += __shfl_xor(ssum, off);
    float inv = 1.f / (ssum + eself + 1e-16f);
    w *= inv;

    int fq = lane & 15, eg = lane >> 4;
    const float4* h4 = (const float4*)h;
    float4 acc = {0.f, 0.f, 0.f, 0.f};
    if (eg == 0) {
        float4 hv = h4[(size_t)wid * 16 + fq];
        float en = eself * inv;
        acc.x = en * hv.x; acc.y = en * hv.y; acc.z = en * hv.z; acc.w = en * hv.w;
    }
    {
        int iters = (dc + 3) >> 2;
        for (int it = 0; it < iters; it++) {
            int j = it * 4 + eg;
            float wj = __shfl(w, j);
            int sj = __shfl(s, j);
            if (j < dc) {
                float4 hv = h4[(size_t)sj * 16 + fq];
                acc.x += wj * hv.x; acc.y += wj * hv.y;
                acc.z += wj * hv.z; acc.w += wj * hv.w;
            }
        }
    }
    for (int base = 64; base < d; base += 64) {
        int cnt = min(64, d - base);
        float w2 = 0.f; int s2 = 0;
        if (lane < cnt) { s2 = col[start + base + lane]; w2 = __expf(lrelu(as_[s2] + adi)) * inv; }
        int iters = (cnt + 3) >> 2;
        for (int it = 0; it < iters; it++) {
            int j = it * 4 + eg;
            float wj = __shfl(w2, j);
            int sj = __shfl(s2, j);
            if (j < cnt) {
                float4 hv = h4[(size_t)sj * 16 + fq];
                acc.x += wj * hv.x; acc.y += wj * hv.y;
                acc.z += wj * hv.z; acc.w += wj * hv.w;
            }
        }
    }
    #pragma unroll
    for (int off = 16; off < 64; off <<= 1) {
        acc.x += __shfl_xor(acc.x, off);
        acc.y += __shfl_xor(acc.y, off);
        acc.z += __shfl_xor(acc.z, off);
        acc.w += __shfl_xor(acc.w, off);
    }
    if (lane < 16) {
        float4 b4 = ((const float4*)bias)[lane];
        float4 o = {acc.x + b4.x, acc.y + b4.y, acc.z + b4.z, acc.w + b4.w};
        if (doElu) { o.x = eluf(o.x); o.y = eluf(o.y); o.z = eluf(o.z); o.w = eluf(o.w); }
        ushort4 ob;
        ob.x = f2bf(o.x); ob.y = f2bf(o.y); ob.z = f2bf(o.z); ob.w = f2bf(o.w);
        ((ushort4*)out)[(size_t)wid * 16 + lane] = ob;
    }
}

// ---------------- Aggregation F=16 (fp32 in/out, unchanged) ----------------

__global__ __launch_bounds__(256) void k_agg16(
    const int* __restrict__ rowptr, const int* __restrict__ deg,
    const int* __restrict__ col, const float* __restrict__ as_,
    const float* __restrict__ ad_, const float* __restrict__ h,
    const float* __restrict__ bias, float* __restrict__ out, int N)
{
    int wid = (blockIdx.x * blockDim.x + threadIdx.x) >> 6;
    int lane = threadIdx.x & 63;
    if (wid >= N) return;
    int start = rowptr[wid];
    int d = deg[wid];
    float adi = ad_[wid];
    float eself = __expf(lrelu(as_[wid] + adi));

    int dc = min(d, 64);
    float w = 0.f; int s = 0;
    if (lane < dc) { s = col[start + lane]; w = __expf(lrelu(as_[s] + adi)); }
    float ssum = w;
    for (int j = lane + 64; j < d; j += 64)
        ssum += __expf(lrelu(as_[col[start + j]] + adi));
    #pragma unroll
    for (int off = 32; off; off >>= 1) ssum += __shfl_xor(ssum, off);
    float inv = 1.f / (ssum + eself + 1e-16f);
    w *= inv;

    int fq = lane & 3, eg = lane >> 2;
    const float4* h4 = (const float4*)h;
    float4 acc = {0.f, 0.f, 0.f, 0.f};
    if (eg == 0) {
        float4 hv = h4[(size_t)wid * 4 + fq];
        float en = eself * inv;
        acc.x = en * hv.x; acc.y = en * hv.y; acc.z = en * hv.z; acc.w = en * hv.w;
    }
    {
        int iters = (dc + 15) >> 4;
        for (int it = 0; it < iters; it++) {
            int j = it * 16 + eg;
            float wj = __shfl(w, j);
            int sj = __shfl(s, j);
            if (j < dc) {
                float4 hv = h4[(size_t)sj * 4 + fq];
                acc.x += wj * hv.x; acc.y += wj * hv.y;
                acc.z += wj * hv.z; acc.w += wj * hv.w;
            }
        }
    }
    for (int base = 64; base < d; base += 64) {
        int cnt = min(64, d - base);
        float w2 = 0.f; int s2 = 0;
        if (lane < cnt) { s2 = col[start + base + lane]; w2 = __expf(lrelu(as_[s2] + adi)) * inv; }
        int iters = (cnt + 15) >> 4;
        for (int it = 0; it < iters; it++) {
            int j = it * 16 + eg;
            float wj = __shfl(w2, j);
            int sj = __shfl(s2, j);
            if (j < cnt) {
                float4 hv = h4[(size_t)sj * 4 + fq];
                acc.x += wj * hv.x; acc.y += wj * hv.y;
                acc.z += wj * hv.z; acc.w += wj * hv.w;
            }
        }
    }
    #pragma unroll
    for (int off = 4; off < 64; off <<= 1) {
        acc.x += __shfl_xor(acc.x, off);
        acc.y += __shfl_xor(acc.y, off);
        acc.z += __shfl_xor(acc.z, off);
        acc.w += __shfl_xor(acc.w, off);
    }
    if (lane < 4) {
        float4 b4 = ((const float4*)bias)[lane];
        float4 o = {acc.x + b4.x, acc.y + b4.y, acc.z + b4.z, acc.w + b4.w};
        ((float4*)out)[(size_t)wid * 4 + lane] = o;
    }
}

// ---------------- BatchNorm stats ----------------

__global__ __launch_bounds__(256) void k_bnstat(const float* __restrict__ logits,
                                                float* __restrict__ bn, int N) {
    int t = threadIdx.x;
    int c = t & 15;
    int g = (blockIdx.x * blockDim.x + t) >> 4;
    int stride = (gridDim.x * blockDim.x) >> 4;
    float s = 0.f, s2 = 0.f;
    for (int r = g; r < N; r += stride) {
        float v = logits[r * 16 + c];
        s += v;
        s2 += v * v;
    }
    s += __shfl_xor(s, 16);  s += __shfl_xor(s, 32);
    s2 += __shfl_xor(s2, 16); s2 += __shfl_xor(s2, 32);
    if ((t & 63) < 16) {
        atomicAdd(&bn[c], s);
        atomicAdd(&bn[16 + c], s2);
    }
}

// ---------------- BN apply + log_softmax + out (dtype-branched) ----------------

__global__ __launch_bounds__(256) void k_final(
    const float* __restrict__ logits, const float* __restrict__ bn,
    const float* __restrict__ gamma, const float* __restrict__ beta,
    const void* __restrict__ x1, void* __restrict__ out, int N)
{
    int f = detect_bf16(x1);
    int r = blockIdx.x * blockDim.x + threadIdx.x;
    if (r >= N) return;
    float invN = 1.f / (float)N;
    float y[16];
    float mx = -1e30f;
    #pragma unroll
    for (int c = 0; c < 16; c++) {
        float mu = bn[c] * invN;
        float var = bn[16 + c] * invN - mu * mu;
        float v = (logits[r * 16 + c] - mu) * rsqrtf(var + 1e-5f);
        v = v * gamma[c] + beta[c];
        y[c] = v;
        mx = fmaxf(mx, v);
    }
    float se = 0.f;
    #pragma unroll
    for (int c = 0; c < 16; c++) se += __expf(y[c] - mx);
    float lse = mx + __logf(se);
    #pragma unroll
    for (int c = 0; c < 16; c++) {
        float v = y[c] - lse;
        if (f) ((__hip_bfloat16*)out)[r * 16 + c] = __float2bfloat16(v);
        else   ((float*)out)[r * 16 + c] = v;
    }
}

// ---------------- launch ----------------

extern "C" void kernel_launch(void* const* d_in, const int* in_sizes, int n_in,
                              void* d_out, int out_size, void* d_ws, size_t ws_size,
                              hipStream_t stream) {
    const void* x1  = d_in[0];
    const void* x2  = d_in[1];
    const int*  ei1 = (const int*)d_in[2];
    const int*  ei2 = (const int*)d_in[3];

    const int N = in_sizes[0] / 64;
    const int E = in_sizes[2] / 2;
    const int nb = (N + 255) >> 8;
    const int NB = 2 * nb;
    const int chunk = (2 * E + NBLK - 1) / NBLK;

    char* p = (char*)d_ws;
    auto alloc = [&](size_t bytes) {
        void* q = (void*)p;
        p += (bytes + 255) & ~(size_t)255;
        return q;
    };
    float* bn       = (float*)alloc(256);                   // zeroed by memset
    unsigned short* h0 = (unsigned short*)alloc((size_t)N * 64 * 2);  // bf16
    unsigned short* h1 = (unsigned short*)alloc((size_t)N * 64 * 2);  // bf16
    float* hlin     = (float*)alloc((size_t)N * 64 * 4);
    float* as_      = (float*)alloc((size_t)N * 4);
    float* ad_      = (float*)alloc((size_t)N * 4);
    int* rowptr1    = (int*)alloc((size_t)N * 4);
    int* deg1       = (int*)alloc((size_t)N * 4);
    int* rowptr2    = (int*)alloc((size_t)N * 4);
    int* deg2       = (int*)alloc((size_t)N * 4);
    int* col1       = (int*)alloc((size_t)nb * CAP * 4);    // aliased as logits later
    int* col2       = (int*)alloc((size_t)nb * CAP * 4);
    int* counts     = (int*)alloc((size_t)NB * NBLK * 4);
    int* bfill      = (int*)alloc((size_t)NB * 4);
    float* P        = (float*)alloc(P_TOTAL * 4);
    float* logits   = (float*)col1;  // col1 dead after layer-0 agg

    // bedge aliases h0/h1/hlin head: 38.4MB <= 12.8+12.8+25.6MB contiguous;
    // consumed by k_bucket2 before any h/hlin write.
    int2* bedge   = (int2*)h0;
    int2* bedge2p = bedge + (size_t)nb * CAP;

    hipMemsetAsync(bn, 0, 256, stream);

    const int TB = 256;
    int gN = (N + TB - 1) / TB;
    int gW = (N + 3) / 4;
    int nt = (N + 63) / 64;
    int gT = nt < 512 ? nt : 512;

    Ptrs15 pp;
    pp.p[0] = d_in[4];  pp.p[1] = d_in[8];   pp.p[2] = d_in[12];
    pp.p[3] = d_in[5];  pp.p[4] = d_in[6];   pp.p[5] = d_in[7];
    pp.p[6] = d_in[9];  pp.p[7] = d_in[10];  pp.p[8] = d_in[11];
    pp.p[9] = d_in[13]; pp.p[10] = d_in[14]; pp.p[11] = d_in[15];
    pp.p[12] = d_in[16]; pp.p[13] = d_in[17]; pp.p[14] = x1;
    k_params<<<14, 256, 0, stream>>>(pp, P);

    // CSR build: count -> scan -> place -> per-bucket node sort
    k_count<<<NBLK, TB, 0, stream>>>(ei1, ei2, E, counts, nb, NB, chunk);
    k_scan<<<NB, TB, 0, stream>>>(counts, bfill);
    k_place<<<NBLK, TB, 0, stream>>>(ei1, ei2, E, counts, bedge, nb, NB, chunk);
    k_bucket2<<<NB, TB, 0, stream>>>(bfill, bedge, rowptr1, deg1, col1,
                                     bfill + nb, bedge2p, rowptr2, deg2, col2, nb, N);

    // Layer 0: x1 (raw) @ W0 -> hlin; aggregate graph1 -> h0 (elu, bf16)
    k_gemm_mfma<64, 64><<<gT, TB, 0, stream>>>(
        x1, 1, x1, 0, P + P_W0, P + P_AS0, P + P_AD0, hlin, as_, ad_, N, nt);
    k_agg64<<<gW, TB, 0, stream>>>(rowptr1, deg1, col1, as_, ad_, hlin, P + P_B0, h0, N, 1);

    // Layer 1: [h0 bf16 | x2 raw] @ W1 -> hlin; aggregate graph2 -> h1 (elu, bf16)
    k_gemm_mfma<128, 64><<<gT, TB, 0, stream>>>(
        h0, 0, x2, 1, P + P_W1, P + P_AS1, P + P_AD1, hlin, as_, ad_, N, nt);
    k_agg64<<<gW, TB, 0, stream>>>(rowptr2, deg2, col2, as_, ad_, hlin, P + P_B1, h1, N, 1);

    // Layer 2: [h0 | h1] @ W2 -> hlin(:,:16); aggregate graph2 -> logits
    k_gemm_mfma<128, 16><<<gT, TB, 0, stream>>>(
        h0, 0, h1, 0, P + P_W2, P + P_AS2, P + P_AD2, hlin, as_, ad_, N, nt);
    k_agg16<<<gW, TB, 0, stream>>>(rowptr2, deg2, col2, as_, ad_, hlin, P + P_B2, logits, N);

    // BN + log_softmax
    k_bnstat<<<256, TB, 0, stream>>>(logits, bn, N);
    k_final<<<gN, TB, 0, stream>>>(logits, bn, P + P_GAMMA, P + P_BETA, x1, d_out, N);
}